// Round 4
// baseline (509.220 us; speedup 1.0000x reference)
//
#include <hip/hip_runtime.h>
#include <hip/hip_bf16.h>
#include <cstdint>
#include <cstddef>

typedef __bf16 bf16;
typedef __attribute__((ext_vector_type(8))) __bf16 bf16x8;
typedef __attribute__((ext_vector_type(4))) float f32x4;

#define B_SZ  8192
#define NAGENT 8
#define NA_N  16
#define OBS_DD 2048
#define ACT_DD 128
#define IN_DD 2176
#define H1_D  1024
#define H2_D  1024

#define BM 256
#define BN 256
#define BK 32
#define GRID_M (B_SZ / BM)   // 32
#define GRID_N (1024 / BN)   // 4

__device__ __forceinline__ void gload16(const void* g, void* l) {
    __builtin_amdgcn_global_load_lds(
        (__attribute__((address_space(1))) void*)(g),
        (__attribute__((address_space(3))) void*)(l), 16, 0, 0);
}

// ---------- preprocessing (verified rounds 1-3) ----------

__global__ void k_convert_x(const float* __restrict__ obs,
                            const float* __restrict__ act,
                            bf16* __restrict__ xb) {
    const int chunks = IN_DD / 8;          // 272
    int idx = blockIdx.x * blockDim.x + threadIdx.x;
    if (idx >= B_SZ * chunks) return;
    int b = idx / chunks;
    int c8 = idx - b * chunks;
    const float* src = (c8 < OBS_DD / 8)
        ? (obs + (size_t)b * OBS_DD + c8 * 8)
        : (act + (size_t)b * ACT_DD + (c8 - OBS_DD / 8) * 8);
    float4 v0 = ((const float4*)src)[0];
    float4 v1 = ((const float4*)src)[1];
    bf16x8 o;
    o[0] = (bf16)v0.x; o[1] = (bf16)v0.y; o[2] = (bf16)v0.z; o[3] = (bf16)v0.w;
    o[4] = (bf16)v1.x; o[5] = (bf16)v1.y; o[6] = (bf16)v1.z; o[7] = (bf16)v1.w;
    ((bf16x8*)(xb + (size_t)b * IN_DD))[c8] = o;
}

__global__ void k_transpose_w(const float* __restrict__ src, bf16* __restrict__ dst,
                              int K, int H, int maskStart) {
    __shared__ float tile[32][33];
    int a = blockIdx.z;
    int k0 = blockIdx.x * 32, h0 = blockIdx.y * 32;
    const float* s = src + (size_t)a * K * H;
    bf16* d = dst + (size_t)a * K * H;
    int tx = threadIdx.x, ty = threadIdx.y;
    #pragma unroll
    for (int i = 0; i < 32; i += 8) {
        int k = k0 + ty + i;
        float v = s[(size_t)k * H + h0 + tx];
        if (k >= maskStart) {
            int g = k - maskStart;
            if ((g >> 4) == a) v = 0.f;
        }
        tile[ty + i][tx] = v;
    }
    __syncthreads();
    #pragma unroll
    for (int i = 0; i < 32; i += 8) {
        d[(size_t)(h0 + ty + i) * K + k0 + tx] = (bf16)tile[tx][ty + i];
    }
}

__global__ void k_transpose_w3(const float* __restrict__ src, bf16* __restrict__ dst) {
    int idx = blockIdx.x * blockDim.x + threadIdx.x;
    if (idx >= NAGENT * NA_N * H2_D) return;
    int a = idx / (NA_N * H2_D);
    int n = (idx / H2_D) % NA_N;
    int k = idx % H2_D;
    dst[idx] = (bf16)src[(size_t)a * H2_D * NA_N + (size_t)k * NA_N + n];
}

// out[b, a*16+n] = b3[a,n]  (bias pre-init; fused L3 atomically accumulates)
__global__ void k_init_out(const float* __restrict__ b3, float* __restrict__ out) {
    int i = blockIdx.x * blockDim.x + threadIdx.x;
    if (i < B_SZ * NAGENT * NA_N) out[i] = b3[i & 127];
}

// ---------- 256x256x32 ring-4 deep-pipeline GEMM ----------
// Ring of 4 LDS slots (32 KB each: A 256x32 + B 256x32), both operands staged
// 3 K-tiles ahead; counted vmcnt(8) drains only the oldest tile's 4 loads.
// FUSE=0: C = relu(A@B^T + bias) stored bf16.
// FUSE=1: h2 tile kept in LDS; fused L3: atomicAdd(out, h2_tile @ W3T_slice).
template<int FUSE>
__global__ __launch_bounds__(512, 2)
void k_gemm256(const bf16* __restrict__ Ain, size_t aStride, int lda,
               const bf16* __restrict__ Bw, const float* __restrict__ bias,
               bf16* __restrict__ Cout, size_t cStride, int K,
               int aOff, int gridZ,
               const bf16* __restrict__ W3Tp, float* __restrict__ outp) {
    extern __shared__ bf16 lds[];   // 65536 elems = 128 KiB; slot s at s*16384

    const int tid = threadIdx.x;
    const int w = tid >> 6;
    const int l = tid & 63;

    // XCD-chunked remap (nwg = 128*gridZ, % 8 == 0)
    int flat = blockIdx.x + GRID_M * (blockIdx.y + GRID_N * blockIdx.z);
    int q8 = (GRID_M * GRID_N * gridZ) >> 3;
    int lin2 = (flat & 7) * q8 + (flat >> 3);
    const int mt = lin2 % GRID_M;
    int rest = lin2 / GRID_M;
    const int ntile = rest % GRID_N;
    const int az = rest / GRID_N;
    const int aw = az + aOff;

    const int rowBase = mt * BM;
    const int colBase = ntile * BN;
    const bf16* Aag = Ain + (size_t)az * aStride;
    const bf16* Bag = Bw + (size_t)aw * (size_t)1024 * K;

    const int wr = (w >> 2) * 128;   // wave rows (2M)
    const int wc = (w & 3) * 64;     // wave cols (4N)
    const int lr = l & 15;
    const int lq = l >> 4;

    // fragment LDS addressing (elems). Rows are 32 elems (64 B = 4 chunks of 16 B);
    // chunk swizzle: phys = logical ^ (row & 3); row&3 == lr&3 for all frags.
    const int swz = (lq ^ (lr & 3)) * 8;
    const int rA = (wr + lr) * 32 + swz;          // + m*512
    const int rB = 8192 + (wc + lr) * 32 + swz;   // + n*512

    // staging: per wave-issue j: rows j*128 + w*16 + (l>>2); source col chunk
    // pre-swizzled: logical = (l&3) ^ ((l>>2)&3)  (dest chunk index = j*512+w*64+l)
    const int sR = w * 16 + (l >> 2);
    const int sC = ((l & 3) ^ ((l >> 2) & 3)) * 8;
    const bf16* pA0 = Aag + (size_t)(rowBase + sR) * lda + sC;
    const bf16* pA1 = Aag + (size_t)(rowBase + 128 + sR) * lda + sC;
    const bf16* pB0 = Bag + (size_t)(colBase + sR) * K + sC;
    const bf16* pB1 = Bag + (size_t)(colBase + 128 + sR) * K + sC;

    const int nkt = K / BK;

#define STAGE_A(t3) do {                                                    \
        bf16* d_ = &lds[(((t3) & 3) * 16384) + w * 512];                    \
        gload16(pA0 + (t3) * BK, d_);                                       \
        gload16(pA1 + (t3) * BK, d_ + 4096);                                \
    } while (0)
#define STAGE_B(t3) do {                                                    \
        bf16* d_ = &lds[(((t3) & 3) * 16384) + 8192 + w * 512];             \
        gload16(pB0 + (t3) * BK, d_);                                       \
        gload16(pB1 + (t3) * BK, d_ + 4096);                                \
    } while (0)

    f32x4 acc[8][4] = {};
    bf16x8 av0, av1, av2, av3, bv[4];

    // prologue: stage tiles 0,1,2 (12 loads/wave in flight)
    STAGE_A(0); STAGE_B(0);
    STAGE_A(1); STAGE_B(1);
    STAGE_A(2); STAGE_B(2);
    asm volatile("s_waitcnt vmcnt(8)" ::: "memory");   // tile 0 landed
    __builtin_amdgcn_s_barrier();

    for (int t = 0; t < nkt; ++t) {
        const int sb = (t & 3) * 16384;

        // ---- phase 0: read A m0-3 + B n0-3; stage A(t+3); MFMA m0-3
        av0 = *(const bf16x8*)&lds[sb + rA + 0 * 512];
        av1 = *(const bf16x8*)&lds[sb + rA + 1 * 512];
        av2 = *(const bf16x8*)&lds[sb + rA + 2 * 512];
        av3 = *(const bf16x8*)&lds[sb + rA + 3 * 512];
        bv[0] = *(const bf16x8*)&lds[sb + rB + 0 * 512];
        bv[1] = *(const bf16x8*)&lds[sb + rB + 1 * 512];
        bv[2] = *(const bf16x8*)&lds[sb + rB + 2 * 512];
        bv[3] = *(const bf16x8*)&lds[sb + rB + 3 * 512];
        if (t + 3 < nkt) STAGE_A(t + 3);
        __builtin_amdgcn_s_barrier();
        __builtin_amdgcn_s_setprio(1);
        #pragma unroll
        for (int n = 0; n < 4; ++n) {
            acc[0][n] = __builtin_amdgcn_mfma_f32_16x16x32_bf16(av0, bv[n], acc[0][n], 0, 0, 0);
            acc[1][n] = __builtin_amdgcn_mfma_f32_16x16x32_bf16(av1, bv[n], acc[1][n], 0, 0, 0);
            acc[2][n] = __builtin_amdgcn_mfma_f32_16x16x32_bf16(av2, bv[n], acc[2][n], 0, 0, 0);
            acc[3][n] = __builtin_amdgcn_mfma_f32_16x16x32_bf16(av3, bv[n], acc[3][n], 0, 0, 0);
        }
        __builtin_amdgcn_s_setprio(0);
        __builtin_amdgcn_s_barrier();

        // ---- phase 1: read A m4-7; stage B(t+3); MFMA m4-7; counted vmcnt
        av0 = *(const bf16x8*)&lds[sb + rA + 4 * 512];
        av1 = *(const bf16x8*)&lds[sb + rA + 5 * 512];
        av2 = *(const bf16x8*)&lds[sb + rA + 6 * 512];
        av3 = *(const bf16x8*)&lds[sb + rA + 7 * 512];
        if (t + 3 < nkt) STAGE_B(t + 3);
        __builtin_amdgcn_s_barrier();
        __builtin_amdgcn_s_setprio(1);
        #pragma unroll
        for (int n = 0; n < 4; ++n) {
            acc[4][n] = __builtin_amdgcn_mfma_f32_16x16x32_bf16(av0, bv[n], acc[4][n], 0, 0, 0);
            acc[5][n] = __builtin_amdgcn_mfma_f32_16x16x32_bf16(av1, bv[n], acc[5][n], 0, 0, 0);
            acc[6][n] = __builtin_amdgcn_mfma_f32_16x16x32_bf16(av2, bv[n], acc[6][n], 0, 0, 0);
            acc[7][n] = __builtin_amdgcn_mfma_f32_16x16x32_bf16(av3, bv[n], acc[7][n], 0, 0, 0);
        }
        __builtin_amdgcn_s_setprio(0);
        if (t + 3 < nkt) {
            asm volatile("s_waitcnt vmcnt(8)" ::: "memory");   // tile t+1 landed; t+2,t+3 in flight
        } else if (t + 2 < nkt) {
            asm volatile("s_waitcnt vmcnt(4)" ::: "memory");   // tile t+1 landed; t+2 in flight
        } else {
            asm volatile("s_waitcnt vmcnt(0)" ::: "memory");   // tail drain
        }
        __builtin_amdgcn_s_barrier();
    }
#undef STAGE_A
#undef STAGE_B

    // ---- epilogue: bias + relu -> swizzled C-LDS tile [256][256] bf16 (verified r3)
    __syncthreads();
    const float* bAg = bias + (size_t)aw * 1024;
    float bb4[4];
    #pragma unroll
    for (int n = 0; n < 4; ++n) bb4[n] = bAg[colBase + wc + n * 16 + lr];
    #pragma unroll
    for (int m = 0; m < 8; ++m)
        #pragma unroll
        for (int n = 0; n < 4; ++n)
            #pragma unroll
            for (int r = 0; r < 4; ++r) {
                float v = acc[m][n][r] + bb4[n];
                v = fmaxf(v, 0.f);
                int row = wr + m * 16 + lq * 4 + r;
                int col = wc + n * 16 + lr;
                lds[row * 256 + ((((col >> 3) ^ (row & 7)) << 3) | (col & 7))] = (bf16)v;
            }
    __syncthreads();

    if constexpr (!FUSE) {
        bf16* Cg = Cout + (size_t)az * cStride + (size_t)rowBase * 1024 + colBase;
        const int er = tid >> 5;
        const int ec = tid & 31;
        #pragma unroll
        for (int i = 0; i < 16; ++i) {
            int row = i * 16 + er;
            int phys = ec ^ (row & 7);
            *(bf16x8*)&Cg[(size_t)row * 1024 + ec * 8] =
                *(const bf16x8*)&lds[row * 256 + phys * 8];
        }
    } else {
        // fused L3: h2 tile (256 rows, k-slice [colBase,colBase+256)) x W3T[aw]
        const bf16* w3a = W3Tp + (size_t)aw * NA_N * H2_D;
        f32x4 oacc[2] = {};
        const int frow0 = w * 32;
        #pragma unroll
        for (int ks = 0; ks < 8; ++ks) {
            bf16x8 bfrag = *(const bf16x8*)&w3a[(size_t)lr * H2_D + colBase + ks * 32 + lq * 8];
            #pragma unroll
            for (int mm = 0; mm < 2; ++mm) {
                int row = frow0 + mm * 16 + lr;
                int lc = (ks * 4 + lq) ^ (row & 7);
                bf16x8 afrag = *(const bf16x8*)&lds[row * 256 + lc * 8];
                oacc[mm] = __builtin_amdgcn_mfma_f32_16x16x32_bf16(afrag, bfrag, oacc[mm], 0, 0, 0);
            }
        }
        #pragma unroll
        for (int mm = 0; mm < 2; ++mm)
            #pragma unroll
            for (int r = 0; r < 4; ++r)
                atomicAdd(&outp[(size_t)(rowBase + frow0 + mm * 16 + lq * 4 + r) * 128
                                + aw * NA_N + lr], oacc[mm][r]);
    }
}

// ---------- launcher ----------
extern "C" void kernel_launch(void* const* d_in, const int* in_sizes, int n_in,
                              void* d_out, int out_size, void* d_ws, size_t ws_size,
                              hipStream_t stream) {
    const float* obs = (const float*)d_in[0];
    const float* act = (const float*)d_in[1];
    const float* W1 = (const float*)d_in[2];
    const float* b1 = (const float*)d_in[3];
    const float* W2 = (const float*)d_in[4];
    const float* b2 = (const float*)d_in[5];
    const float* W3 = (const float*)d_in[6];
    const float* b3 = (const float*)d_in[7];
    float* out = (float*)d_out;

    const size_t SZ_XB  = (size_t)B_SZ * IN_DD * 2;
    const size_t SZ_W1T = (size_t)NAGENT * H1_D * IN_DD * 2;
    const size_t SZ_W2T = (size_t)NAGENT * H1_D * H2_D * 2;
    const size_t SZ_W3T = (size_t)NAGENT * NA_N * H2_D * 2;
    const size_t SZ_H1  = (size_t)B_SZ * H1_D * 2;
    const size_t SZ_FIX = SZ_XB + SZ_W1T + SZ_W2T + SZ_W3T;

    char* ws = (char*)d_ws;
    bf16* Xb  = (bf16*)ws;
    bf16* W1T = (bf16*)(ws + SZ_XB);
    bf16* W2T = (bf16*)(ws + SZ_XB + SZ_W1T);
    bf16* W3T = (bf16*)(ws + SZ_XB + SZ_W1T + SZ_W2T);
    char* hbase = ws + SZ_FIX;

    // largest G (agents per pass) that fits: h1 only (h2/L3 fused)
    int G = 8;
    while (G > 1 && ws_size < SZ_FIX + (size_t)G * SZ_H1) G >>= 1;

    (void)hipFuncSetAttribute((const void*)k_gemm256<0>,
                              hipFuncAttributeMaxDynamicSharedMemorySize, 131072);
    (void)hipFuncSetAttribute((const void*)k_gemm256<1>,
                              hipFuncAttributeMaxDynamicSharedMemorySize, 131072);

    // out = b3 broadcast (fused L3 accumulates on top)
    k_init_out<<<(B_SZ * 128 + 255) / 256, 256, 0, stream>>>(b3, out);

    // preprocessing
    {
        int n = B_SZ * (IN_DD / 8);
        k_convert_x<<<(n + 255) / 256, 256, 0, stream>>>(obs, act, Xb);
    }
    k_transpose_w<<<dim3(IN_DD / 32, H1_D / 32, NAGENT), dim3(32, 8), 0, stream>>>(
        W1, W1T, IN_DD, H1_D, OBS_DD);
    k_transpose_w<<<dim3(H1_D / 32, H2_D / 32, NAGENT), dim3(32, 8), 0, stream>>>(
        W2, W2T, H1_D, H2_D, 1 << 30);
    {
        int n = NAGENT * NA_N * H2_D;
        k_transpose_w3<<<(n + 255) / 256, 256, 0, stream>>>(W3, W3T);
    }

    const size_t agElems = (size_t)B_SZ * H1_D;
    bf16* h1 = (bf16*)hbase;

    for (int g0 = 0; g0 < NAGENT; g0 += G) {
        k_gemm256<0><<<dim3(GRID_M, GRID_N, G), 512, 131072, stream>>>(
            Xb, 0, IN_DD, W1T, b1, h1, agElems, IN_DD, g0, G, nullptr, nullptr);
        k_gemm256<1><<<dim3(GRID_M, GRID_N, G), 512, 131072, stream>>>(
            h1, agElems, H1_D, W2T, b2, nullptr, 0, H1_D, g0, G, W3T, out);
    }
    (void)in_sizes; (void)n_in; (void)out_size;
}